// Round 5
// baseline (568.890 us; speedup 1.0000x reference)
//
#include <hip/hip_runtime.h>
#include <hip/hip_bf16.h>
#include <stdint.h>

// Problem constants
#define NQ    2304          // H*W = 48*48 tokens
#define MROWS 4608          // B*NQ
#define DIMC  768
#define NHEAD 12
#define HEADS 24            // B*NH
#define HD    64

typedef unsigned int uint;
typedef unsigned short u16;
typedef __attribute__((ext_vector_type(8))) short s16x8;   // 8 bf16 = 4 VGPR
typedef __attribute__((ext_vector_type(4))) float f32x4;   // mfma acc

#define MFMA16(a, b, c) __builtin_amdgcn_mfma_f32_16x16x32_bf16((a), (b), (c), 0, 0, 0)

static __device__ __forceinline__ float bfbits2f(uint u) {
  union { uint i; float f; } c; c.i = u << 16; return c.f;
}
static __device__ __forceinline__ u16 f2bf(float f) {
  __hip_bfloat16 h = __float2bfloat16(f);
  union { __hip_bfloat16 h; u16 u; } c; c.h = h; return c.u;
}
static __device__ __forceinline__ void dec8(uint4 p, float* f) {
  f[0] = bfbits2f(p.x & 0xFFFFu); f[1] = bfbits2f(p.x >> 16);
  f[2] = bfbits2f(p.y & 0xFFFFu); f[3] = bfbits2f(p.y >> 16);
  f[4] = bfbits2f(p.z & 0xFFFFu); f[5] = bfbits2f(p.z >> 16);
  f[6] = bfbits2f(p.w & 0xFFFFu); f[7] = bfbits2f(p.w >> 16);
}
// dual-dtype 8-element load -> fp32 (bf=1: bf16, bf=0: fp32)
static __device__ __forceinline__ void ld8(const void* p, size_t idx, int bf, float* f) {
  if (bf) { dec8(*(const uint4*)((const u16*)p + idx), f); }
  else {
    const float4* q = (const float4*)((const float*)p + idx);
    float4 a = q[0], b = q[1];
    f[0] = a.x; f[1] = a.y; f[2] = a.z; f[3] = a.w;
    f[4] = b.x; f[5] = b.y; f[6] = b.z; f[7] = b.w;
  }
}
static __device__ __forceinline__ float ld1(const void* p, size_t idx, int bf) {
  return bf ? bfbits2f(((const u16*)p)[idx]) : ((const float*)p)[idx];
}
// dual-dtype 8-element load -> packed bf16 (uint4)
static __device__ __forceinline__ uint4 ld8_to_bf(const void* p, size_t idx, int bf) {
  if (bf) return *(const uint4*)((const u16*)p + idx);
  float f[8]; ld8(p, idx, 0, f);
  uint4 u;
  u.x = (uint)f2bf(f[0]) | ((uint)f2bf(f[1]) << 16);
  u.y = (uint)f2bf(f[2]) | ((uint)f2bf(f[3]) << 16);
  u.z = (uint)f2bf(f[4]) | ((uint)f2bf(f[5]) << 16);
  u.w = (uint)f2bf(f[6]) | ((uint)f2bf(f[7]) << 16);
  return u;
}

// ---------------------------------------------------------------------------
// K0: dtype detector (unchanged — PASSED twice; do not touch).
// ---------------------------------------------------------------------------
__global__ __launch_bounds__(64) void detect_k(const u16* __restrict__ x,
                                               int* __restrict__ mode) {
  int t = threadIdx.x;
  int cnt = 0;
  for (int i = 0; i < 32; ++i) {
    uint u = x[(size_t)(t * 32 + i) * 2];
    uint e = (u >> 7) & 0xFFu;
    uint mag = u & 0x7FFFu;
    if (mag == 0 || (e >= 113 && e <= 133)) cnt++;
  }
#pragma unroll
  for (int d = 1; d < 64; d <<= 1) cnt += __shfl_xor(cnt, d);
  if (t == 0) mode[0] = (cnt > 1024) ? 1 : 0;
}

// ---------------------------------------------------------------------------
// K1: QKV projection, MFMA 128x128 tile, BK=32.
// Q written [bh][n][d] unscaled; K written [bh][n][d] PRESCALED by 0.125
// (exact in bf16); V written TRANSPOSED [bh][d][n] (packed uint2 stores).
// ---------------------------------------------------------------------------
__global__ __launch_bounds__(256) void qkv_gemm_k(
    const void* __restrict__ Xp, const void* __restrict__ Wp,
    const void* __restrict__ Bq, const int* __restrict__ mode,
    u16* __restrict__ Q, u16* __restrict__ K, u16* __restrict__ Vt)
{
  __shared__ __align__(16) u16 As[128][40];
  __shared__ __align__(16) u16 Bs[128][40];
  const int bf = mode[0];
  const int t = threadIdx.x;
  const int w = t >> 6, l15 = t & 15, quad = (t >> 4) & 3;
  const int wr = w >> 1, wc = w & 1;
  const int row0 = blockIdx.y << 7, col0 = blockIdx.x << 7;
  const int lr = t >> 1, lk = (t & 1) << 4;

  f32x4 zero4 = {0.f, 0.f, 0.f, 0.f};
  f32x4 acc[4][4];
#pragma unroll
  for (int i = 0; i < 4; ++i)
#pragma unroll
    for (int j = 0; j < 4; ++j) acc[i][j] = zero4;

  for (int kt = 0; kt < DIMC; kt += 32) {
    __syncthreads();
    *(uint4*)&As[lr][lk]     = ld8_to_bf(Xp, (size_t)(row0 + lr) * DIMC + kt + lk, bf);
    *(uint4*)&As[lr][lk + 8] = ld8_to_bf(Xp, (size_t)(row0 + lr) * DIMC + kt + lk + 8, bf);
    *(uint4*)&Bs[lr][lk]     = ld8_to_bf(Wp, (size_t)(col0 + lr) * DIMC + kt + lk, bf);
    *(uint4*)&Bs[lr][lk + 8] = ld8_to_bf(Wp, (size_t)(col0 + lr) * DIMC + kt + lk + 8, bf);
    __syncthreads();
    s16x8 af[4], bfr[4];
#pragma unroll
    for (int i = 0; i < 4; ++i)
      af[i] = *(const s16x8*)&As[(wr << 6) + (i << 4) + l15][quad << 3];
#pragma unroll
    for (int j = 0; j < 4; ++j)
      bfr[j] = *(const s16x8*)&Bs[(wc << 6) + (j << 4) + l15][quad << 3];
#pragma unroll
    for (int i = 0; i < 4; ++i)
#pragma unroll
      for (int j = 0; j < 4; ++j)
        acc[i][j] = MFMA16(af[i], bfr[j], acc[i][j]);
  }

#pragma unroll
  for (int jt = 0; jt < 4; ++jt) {
    int col = col0 + (wc << 6) + (jt << 4) + l15;     // 0..2303, wave-uniform /768
    int which = col / DIMC;
    int rem = col - which * DIMC;
    int head = rem >> 6, d = rem & 63;
    float bv = ld1(Bq, col, bf);
#pragma unroll
    for (int i = 0; i < 4; ++i) {
      int mrow0 = row0 + (wr << 6) + (i << 4) + (quad << 2);   // 4-aligned; NQ%4==0
      int b_ = (mrow0 >= NQ) ? 1 : 0;
      int n0 = mrow0 - b_ * NQ;
      int bh = b_ * NHEAD + head;
      if (which == 0) {
#pragma unroll
        for (int r = 0; r < 4; ++r)
          Q[((size_t)bh * NQ + n0 + r) * HD + d] = f2bf(acc[i][jt][r] + bv);
      } else if (which == 1) {
#pragma unroll
        for (int r = 0; r < 4; ++r)
          K[((size_t)bh * NQ + n0 + r) * HD + d] = f2bf((acc[i][jt][r] + bv) * 0.125f);
      } else {
        uint2 pk;
        pk.x = (uint)f2bf(acc[i][jt][0] + bv) | ((uint)f2bf(acc[i][jt][1] + bv) << 16);
        pk.y = (uint)f2bf(acc[i][jt][2] + bv) | ((uint)f2bf(acc[i][jt][3] + bv) << 16);
        *(uint2*)&Vt[((size_t)bh * HD + d) * NQ + n0] = pk;
      }
    }
  }
}

// ---------------------------------------------------------------------------
// K2: MFMA flash attention, bias folded into QK^T via one-hot K-augmentation.
// Block = (64 q-rows, 1 head); 4 waves. Augmented K-dim = 160:
//   ch 0..63   = k * 0.125            (prescaled in qkv_gemm)
//   ch 64..111 = onehot(kh(key))      -> selects Bh[row][kh] from A-side
//   ch 112..159= onehot(kw(key))      -> selects Bw[row][kw]
// A-side frags qa[0..4] = [q(64) | Bh(48) | Bw(48)] per row — loop-invariant.
// LDS 39.9 KB -> 4 blocks/CU. Bias prologue scratch overlays Vt/Ps region.
// ---------------------------------------------------------------------------
__global__ __launch_bounds__(256) void attn_k(
    const u16* __restrict__ Qw, const u16* __restrict__ Kw,
    const u16* __restrict__ Vtw,
    const void* __restrict__ rph, const void* __restrict__ rpw,
    const int* __restrict__ mode,
    u16* __restrict__ Aout)
{
  __shared__ __align__(16) u16 smem[19968];              // 39936 B
  u16 (*Kaug)[168] = (u16(*)[168])smem;                  // 64 x 168 (10752 u16)
  u16 (*Vt)[72]    = (u16(*)[72])(smem + 10752);         // 64 x 72   (4608 u16)
  u16* Psw         = smem + 10752 + 4608;                // 4 x 16 x 72 (4608 u16)
  u16 (*Bias)[96]  = (u16(*)[96])(smem + 10752);         // prologue overlay 64x96

  const int bf = mode[0];
  const int bh = blockIdx.y;
  const int q0 = blockIdx.x << 6;
  const int t = threadIdx.x;
  const int w = t >> 6, l15 = t & 15, quad = (t >> 4) & 3;

  // ---- prologue: bias rows (bf16) into overlay ----
  for (int e = t; e < 64 * 48; e += 256) {
    int r = (e * 10923) >> 19;          // e/48
    int c = e - r * 48;
    int n = q0 + r;
    int qh = (n * 10923) >> 19;         // n/48
    int qw_ = n - qh * 48;
    const u16* qr = Qw + ((size_t)bh * NQ + n) * HD;
    size_t ih = (size_t)(qh - c + 47) * HD;
    size_t iw = (size_t)(qw_ - c + 47) * HD;
    float sh = 0.f, sw = 0.f;
#pragma unroll
    for (int v8 = 0; v8 < 8; ++v8) {
      float fq[8], fh[8], fw[8];
      dec8(*(const uint4*)(qr + (v8 << 3)), fq);
      ld8(rph, ih + (v8 << 3), bf, fh);
      ld8(rpw, iw + (v8 << 3), bf, fw);
#pragma unroll
      for (int j = 0; j < 8; ++j) { sh += fq[j] * fh[j]; sw += fq[j] * fw[j]; }
    }
    Bias[r][c] = f2bf(sh);
    Bias[r][48 + c] = f2bf(sw);
  }
  __syncthreads();

  // ---- A-side augmented frags (registers, loop-invariant) ----
  f32x4 zero4 = {0.f, 0.f, 0.f, 0.f};
  s16x8 qa[5];
  {
    const u16* qfrag = Qw + ((size_t)bh * NQ + q0 + (w << 4) + l15) * HD + (quad << 3);
    qa[0] = *(const s16x8*)(qfrag);
    qa[1] = *(const s16x8*)(qfrag + 32);
    const u16* brow = &Bias[(w << 4) + l15][quad << 3];
    qa[2] = *(const s16x8*)(brow);        // ch  64.. 95 (Bias cols  0..31)
    qa[3] = *(const s16x8*)(brow + 32);   // ch  96..127 (Bias cols 32..63)
    qa[4] = *(const s16x8*)(brow + 64);   // ch 128..159 (Bias cols 64..95)
  }

  f32x4 acc_o[4];
#pragma unroll
  for (int nc = 0; nc < 4; ++nc) acc_o[nc] = zero4;
  float m_st[4] = {-INFINITY, -INFINITY, -INFINITY, -INFINITY};
  float l_st[4] = {0.f, 0.f, 0.f, 0.f};

  const u16* kbase = Kw + (size_t)bh * NQ * HD;
  const u16* vbase = Vtw + (size_t)bh * HD * NQ;
  u16* ps = Psw + w * 1152;               // own wave's 16x72 P block

  for (int kt0 = 0; kt0 < NQ; kt0 += 64) {
    __syncthreads();   // frag reads / prev-tile reads done; Vt/Ps/Kaug reusable
    // K rows (raw copy of prescaled K) — 2 uint4/thread
#pragma unroll
    for (int i = 0; i < 2; ++i) {
      int c = t + (i << 8);
      int row = c >> 3, col8 = (c & 7) << 3;
      *(uint4*)&Kaug[row][col8] = *(const uint4*)(kbase + (size_t)(kt0 + row) * HD + col8);
    }
    // V tile from pre-transposed workspace — 2 uint4/thread
#pragma unroll
    for (int i = 0; i < 2; ++i) {
      int c = t + (i << 8);
      int d = c >> 3, col8 = (c & 7) << 3;
      *(uint4*)&Vt[d][col8] = *(const uint4*)(vbase + (size_t)d * NQ + kt0 + col8);
    }
    // one-hot aug channels — 3 uint4/thread, ones inserted inline
#pragma unroll
    for (int i = 0; i < 3; ++i) {
      int u = t + (i << 8);               // 0..767
      int row = (u * 10923) >> 17;        // u/12
      int seg = u - row * 12;             // 0..11 (8-ch segments of 96)
      int key = kt0 + row;
      int kh = (key * 10923) >> 19;       // key/48
      int kw = key - kh * 48;
      int base = seg << 3;
      uint zw0 = 0, zw1 = 0, zw2 = 0, zw3 = 0;
      int d1 = kh - base;                 // target within seg for onehot_h
      int d2 = 48 + kw - base;            // target for onehot_w
      if ((unsigned)d1 < 8u) {
        uint v = 0x3F80u << ((d1 & 1) << 4);
        if ((d1 >> 1) == 0) zw0 |= v; else if ((d1 >> 1) == 1) zw1 |= v;
        else if ((d1 >> 1) == 2) zw2 |= v; else zw3 |= v;
      }
      if ((unsigned)d2 < 8u) {
        uint v = 0x3F80u << ((d2 & 1) << 4);
        if ((d2 >> 1) == 0) zw0 |= v; else if ((d2 >> 1) == 1) zw1 |= v;
        else if ((d2 >> 1) == 2) zw2 |= v; else zw3 |= v;
      }
      uint4 z; z.x = zw0; z.y = zw1; z.z = zw2; z.w = zw3;
      *(uint4*)&Kaug[row][64 + base] = z;
    }
    __syncthreads();

    // S = [q|Bh|Bw] . Kaug^T : 5 ksteps x 4 nc = 20 mfma
    f32x4 acc_s[4];
#pragma unroll
    for (int nc = 0; nc < 4; ++nc) {
      const u16* kr = &Kaug[(nc << 4) + l15][quad << 3];
      f32x4 a = MFMA16(qa[0], *(const s16x8*)(kr), zero4);
      a = MFMA16(qa[1], *(const s16x8*)(kr + 32), a);
      a = MFMA16(qa[2], *(const s16x8*)(kr + 64), a);
      a = MFMA16(qa[3], *(const s16x8*)(kr + 96), a);
      acc_s[nc] = MFMA16(qa[4], *(const s16x8*)(kr + 128), a);
    }

    // online softmax per row r (scores complete incl. scale+bias)
#pragma unroll
    for (int r = 0; r < 4; ++r) {
      float mx = fmaxf(fmaxf(acc_s[0][r], acc_s[1][r]), fmaxf(acc_s[2][r], acc_s[3][r]));
      mx = fmaxf(mx, __shfl_xor(mx, 1));
      mx = fmaxf(mx, __shfl_xor(mx, 2));
      mx = fmaxf(mx, __shfl_xor(mx, 4));
      mx = fmaxf(mx, __shfl_xor(mx, 8));
      float mn = fmaxf(m_st[r], mx);
      float al = __expf(m_st[r] - mn);
      float sum = 0.f;
#pragma unroll
      for (int nc = 0; nc < 4; ++nc) {
        float p = __expf(acc_s[nc][r] - mn);
        ps[((quad << 2) + r) * 72 + (nc << 4) + l15] = f2bf(p);
        sum += p;
      }
      sum += __shfl_xor(sum, 1);
      sum += __shfl_xor(sum, 2);
      sum += __shfl_xor(sum, 4);
      sum += __shfl_xor(sum, 8);
      l_st[r] = l_st[r] * al + sum;
      m_st[r] = mn;
#pragma unroll
      for (int nc = 0; nc < 4; ++nc) acc_o[nc][r] = acc_o[nc][r] * al;
    }

    // drain wave-private P round-trip
    __builtin_amdgcn_s_waitcnt(0xC07F);   // lgkmcnt(0)

    // O += P V
    s16x8 pf0 = *(const s16x8*)&ps[l15 * 72 + (quad << 3)];
    s16x8 pf1 = *(const s16x8*)&ps[l15 * 72 + 32 + (quad << 3)];
#pragma unroll
    for (int nc = 0; nc < 4; ++nc) {
      s16x8 vb0 = *(const s16x8*)&Vt[(nc << 4) + l15][quad << 3];
      s16x8 vb1 = *(const s16x8*)&Vt[(nc << 4) + l15][32 + (quad << 3)];
      acc_o[nc] = MFMA16(pf0, vb0, acc_o[nc]);
      acc_o[nc] = MFMA16(pf1, vb1, acc_o[nc]);
    }
  }

  // epilogue
  int b_ = bh / NHEAD, head = bh - b_ * NHEAD;
#pragma unroll
  for (int r = 0; r < 4; ++r) {
    float inv = 1.f / l_st[r];
    int token = q0 + (w << 4) + (quad << 2) + r;
    u16* dst = Aout + ((size_t)b_ * NQ + token) * DIMC + (head << 6);
#pragma unroll
    for (int nc = 0; nc < 4; ++nc)
      dst[(nc << 4) + l15] = f2bf(acc_o[nc][r] * inv);
  }
}

// ---------------------------------------------------------------------------
// K3: output projection, MFMA (unchanged from round 4 — not the bottleneck).
// ---------------------------------------------------------------------------
__global__ __launch_bounds__(256) void proj_gemm_k(
    const u16* __restrict__ A, const void* __restrict__ Wp,
    const void* __restrict__ Bp, const int* __restrict__ mode,
    void* __restrict__ Out)
{
  __shared__ __align__(16) u16 As[128][40];
  __shared__ __align__(16) u16 Bs[128][40];
  const int bf = mode[0];
  const int t = threadIdx.x;
  const int w = t >> 6, l15 = t & 15, quad = (t >> 4) & 3;
  const int wr = w >> 1, wc = w & 1;
  const int row0 = blockIdx.y << 7, col0 = blockIdx.x << 7;
  const int lr = t >> 1, lk = (t & 1) << 4;

  f32x4 zero4 = {0.f, 0.f, 0.f, 0.f};
  f32x4 acc[4][4];
#pragma unroll
  for (int i = 0; i < 4; ++i)
#pragma unroll
    for (int j = 0; j < 4; ++j) acc[i][j] = zero4;

  for (int kt = 0; kt < DIMC; kt += 32) {
    __syncthreads();
    *(uint4*)&As[lr][lk]     = *(const uint4*)(A + (size_t)(row0 + lr) * DIMC + kt + lk);
    *(uint4*)&As[lr][lk + 8] = *(const uint4*)(A + (size_t)(row0 + lr) * DIMC + kt + lk + 8);
    *(uint4*)&Bs[lr][lk]     = ld8_to_bf(Wp, (size_t)(col0 + lr) * DIMC + kt + lk, bf);
    *(uint4*)&Bs[lr][lk + 8] = ld8_to_bf(Wp, (size_t)(col0 + lr) * DIMC + kt + lk + 8, bf);
    __syncthreads();
    s16x8 af[4], bfr[4];
#pragma unroll
    for (int i = 0; i < 4; ++i)
      af[i] = *(const s16x8*)&As[(wr << 6) + (i << 4) + l15][quad << 3];
#pragma unroll
    for (int j = 0; j < 4; ++j)
      bfr[j] = *(const s16x8*)&Bs[(wc << 6) + (j << 4) + l15][quad << 3];
#pragma unroll
    for (int i = 0; i < 4; ++i)
#pragma unroll
      for (int j = 0; j < 4; ++j)
        acc[i][j] = MFMA16(af[i], bfr[j], acc[i][j]);
  }

#pragma unroll
  for (int jt = 0; jt < 4; ++jt) {
    int col = col0 + (wc << 6) + (jt << 4) + l15;
    float bv = ld1(Bp, col, bf);
#pragma unroll
    for (int i = 0; i < 4; ++i)
#pragma unroll
      for (int r = 0; r < 4; ++r) {
        int mrow = row0 + (wr << 6) + (i << 4) + (quad << 2) + r;
        float val = acc[i][jt][r] + bv;
        size_t off = (size_t)mrow * DIMC + col;
        if (bf) ((u16*)Out)[off] = f2bf(val);
        else    ((float*)Out)[off] = val;
      }
  }
}

// ---------------------------------------------------------------------------
extern "C" void kernel_launch(void* const* d_in, const int* in_sizes, int n_in,
                              void* d_out, int out_size, void* d_ws, size_t ws_size,
                              hipStream_t stream)
{
  const void* x    = d_in[0];   // (2,48,48,768)
  const void* rph  = d_in[1];   // (95,64)
  const void* rpw  = d_in[2];   // (95,64)
  const void* qkvw = d_in[3];   // (2304,768)
  const void* qkvb = d_in[4];   // (2304,)
  const void* pw   = d_in[5];   // (768,768)
  const void* pb   = d_in[6];   // (768,)

  // Workspace: [mode 16B] q (bh,n,d), k (bh,n,d, prescaled), vt (bh,d,n),
  // aout (b,n,dim) — all bf16.  ~28.3 MB.
  int* mode = (int*)d_ws;
  const size_t qkv_elems = (size_t)HEADS * NQ * HD;   // 3,538,944
  u16* q    = (u16*)((char*)d_ws + 16);
  u16* k    = q + qkv_elems;
  u16* vt   = k + qkv_elems;
  u16* aout = vt + qkv_elems;

  detect_k<<<1, 64, 0, stream>>>((const u16*)x, mode);
  qkv_gemm_k<<<dim3(18, 36), 256, 0, stream>>>(x, qkvw, qkvb, mode, q, k, vt);
  attn_k<<<dim3(NQ / 64, HEADS), 256, 0, stream>>>(q, k, vt, rph, rpw, mode, aout);
  proj_gemm_k<<<dim3(6, 36), 256, 0, stream>>>(aout, pw, pb, mode, d_out);
}